// Round 6
// baseline (163.482 us; speedup 1.0000x reference)
//
#include <hip/hip_runtime.h>
#include <math.h>
#include <stdint.h>

typedef __bf16 bf16_t;
typedef __attribute__((ext_vector_type(8))) __bf16 bf16x8;
typedef __attribute__((ext_vector_type(4))) __bf16 bf16x4;
typedef __attribute__((ext_vector_type(4))) float f32x4;

#define DIM   768
#define HEADS 12
#define HD    64
#define NB    2
#define NQ    2048
#define NKV   2048
#define MROWS 4096
#define NQKV  2304   /* DIM(Q) + 2*DIM(KV) */

// ---- compile-safe fast exp2 (single v_exp_f32 when builtin exists) ----
__device__ __forceinline__ float fast_exp2(float x)
{
#if __has_builtin(__builtin_amdgcn_exp2f)
    return __builtin_amdgcn_exp2f(x);
#else
    return exp2f(x);
#endif
}

// async 16B global -> LDS (m97 trick). LDS dest must be uniform + lane*16.
__device__ __forceinline__ void async_copy16(const bf16_t* g, bf16_t* l)
{
    typedef const __attribute__((address_space(1))) uint32_t* gp_t;
    typedef __attribute__((address_space(3))) uint32_t* lp_t;
    __builtin_amdgcn_global_load_lds((gp_t)(const void*)g, (lp_t)(void*)l, 16, 0, 0);
}

// ---------------- fused prep: casts (z=0,1) + weight transposes (z=2,3,4) ----------------
__global__ void prep_kernel(const float* __restrict__ qs, bf16_t* __restrict__ qs_bf,
                            const float* __restrict__ kvs, bf16_t* __restrict__ kvs_bf,
                            const float* __restrict__ Wq, const float* __restrict__ Wkv,
                            const float* __restrict__ Wproj, bf16_t* __restrict__ Wt,
                            float escale)
{
    __shared__ float tile[32][33];
    const int z = blockIdx.z;
    if (z < 2) {
        const float* in  = z ? kvs : qs;
        bf16_t*      out = z ? kvs_bf : qs_bf;
        const int i = (blockIdx.x * 256 + threadIdx.x) * 8;   // grid.x*2048 == MROWS*DIM
        bf16x8 v;
#pragma unroll
        for (int j = 0; j < 8; j++) v[j] = (bf16_t)in[i + j];
        *(bf16x8*)(out + i) = v;
        return;
    }
    const int N   = (z == 3) ? 2 * DIM : DIM;
    const int nb  = N / 32;
    const int idx = blockIdx.x;
    if (idx >= nb * (DIM / 32)) return;
    const float* W = (z == 2) ? Wq : (z == 3) ? Wkv : Wproj;
    bf16_t* T = Wt + ((z == 2) ? (size_t)0 : (z == 3) ? (size_t)DIM * DIM
                                                      : (size_t)NQKV * DIM);
    const float scl = (z == 2) ? escale : 1.0f;
    const int n0 = (idx % nb) * 32, k0 = (idx / nb) * 32;
    const int tx = threadIdx.x & 31, ty = threadIdx.x >> 5;
#pragma unroll
    for (int i = 0; i < 4; i++)
        tile[ty + i * 8][tx] = W[(size_t)(k0 + ty + i * 8) * N + n0 + tx];
    __syncthreads();
#pragma unroll
    for (int i = 0; i < 4; i++)
        T[(size_t)(n0 + ty + i * 8) * DIM + k0 + tx] = (bf16_t)(tile[tx][ty + i * 8] * scl);
}

// ---------------- GEMM: 128xTN tile, BK=64, T3 2-phase double-buffered staging --------
// MODE 0: fused QKV (N=2304). Q (pre-scaled via Wq) / K stored plain [b,tok,768];
//         V^T stored KV-PERMUTED so attn's PV A-frags are single contiguous b128.
// MODE 1: proj (fp32 out + bias)
// Round-4 verified: 2-phase dbuf (stage(t+1) before compute(t), ONE barrier/step) -4.4us.
template<int MODE, int TN>
__global__ __launch_bounds__(256)
void gemm_bk64(const bf16_t* __restrict__ Aq, const bf16_t* __restrict__ Akv,
               const bf16_t* __restrict__ Bt,
               bf16_t* __restrict__ Qb, bf16_t* __restrict__ Kb, bf16_t* __restrict__ Vtb,
               float* __restrict__ ofp, const float* __restrict__ bias)
{
    constexpr int K  = DIM;
    constexpr int NT = TN / 32;
    constexpr int ABLK = 128 * 64;
    constexpr int BBLK = TN * 64;
    constexpr int STEP = ABLK + BBLK;                      // one staging buffer
    constexpr int TRELEMS = (MODE == 0) ? 128 * 136 : 0;   // V-transpose epilogue scratch
    constexpr int SELEMS = (2 * STEP > TRELEMS) ? 2 * STEP : TRELEMS;
    __shared__ __align__(16) bf16_t smem[SELEMS];

    const int tid  = threadIdx.x;
    const int wave = tid >> 6, lane = tid & 63;
    const int quad = lane >> 4, l16 = lane & 15, l7 = l16 & 7;
    const int bm = blockIdx.x * 128, bn = blockIdx.y * TN;
    const int wm = (wave >> 1) * 64, wn = (wave & 1) * (TN / 2);

    const bf16_t* A = (MODE == 0) ? (bn < DIM ? Aq : Akv) : Aq;

    const int srow = tid >> 3;
    const int scol = ((tid & 7) ^ (srow & 7)) * 8;
    const bf16_t* Ag[4];
    const bf16_t* Bg[NT];
#pragma unroll
    for (int i = 0; i < 4; i++)
        Ag[i] = A + (size_t)(bm + i * 32 + srow) * K + scol;
#pragma unroll
    for (int i = 0; i < NT; i++)
        Bg[i] = Bt + (size_t)(bn + i * 32 + srow) * K + scol;

    f32x4 acc[4][NT] = {};

    // prologue: stage K-step 0 into buf 0
    {
        bf16_t* AsL = smem + tid * 8;
        bf16_t* BsL = smem + ABLK + tid * 8;
#pragma unroll
        for (int i = 0; i < 4; i++) async_copy16(Ag[i], AsL + i * 2048);
#pragma unroll
        for (int i = 0; i < NT; i++) async_copy16(Bg[i], BsL + i * 2048);
    }
    __syncthreads();

    for (int t = 0; t < K / 64; t++) {
        bf16_t* Ac = smem + (t & 1) * STEP;
        bf16_t* Bc = Ac + ABLK;

        // prefetch next K-step into the other buffer (latency hides under compute)
        if (t + 1 < K / 64) {
            bf16_t* AsL = smem + ((t + 1) & 1) * STEP + tid * 8;
            bf16_t* BsL = AsL + ABLK;
            const int k1 = (t + 1) * 64;
#pragma unroll
            for (int i = 0; i < 4; i++) async_copy16(Ag[i] + k1, AsL + i * 2048);
#pragma unroll
            for (int i = 0; i < NT; i++) async_copy16(Bg[i] + k1, BsL + i * 2048);
        }

#pragma unroll
        for (int ks = 0; ks < 2; ks++) {
            const int pc = ((ks * 4 + quad) ^ l7) * 8;
            bf16x8 af[4], bfr[NT];
#pragma unroll
            for (int mt = 0; mt < 4; mt++)
                af[mt] = *(const bf16x8*)(&Ac[(wm + mt * 16 + l16) * 64 + pc]);
#pragma unroll
            for (int nt = 0; nt < NT; nt++)
                bfr[nt] = *(const bf16x8*)(&Bc[(wn + nt * 16 + l16) * 64 + pc]);
#pragma unroll
            for (int mt = 0; mt < 4; mt++)
#pragma unroll
                for (int nt = 0; nt < NT; nt++)
                    acc[mt][nt] = __builtin_amdgcn_mfma_f32_16x16x32_bf16(
                        af[mt], bfr[nt], acc[mt][nt], 0, 0, 0);
        }

        // single barrier per K-step: drains the prefetch (issued a compute-phase ago)
        // and fences reads of buf(t) before iteration t+1's prefetch overwrites it
        __syncthreads();
    }

    // ---- epilogue; C layout: col = lane&15, row = quad*4 + reg ----
    if (MODE == 1) {
#pragma unroll
        for (int mt = 0; mt < 4; mt++)
#pragma unroll
            for (int nt = 0; nt < NT; nt++)
#pragma unroll
                for (int r = 0; r < 4; r++) {
                    const int gm = bm + wm + mt * 16 + quad * 4 + r;
                    const int gn = bn + wn + nt * 16 + l16;
                    ofp[(size_t)gm * DIM + gn] = acc[mt][nt][r] + bias[gn];
                }
    } else if (bn < DIM) {
#pragma unroll
        for (int mt = 0; mt < 4; mt++)
#pragma unroll
            for (int nt = 0; nt < NT; nt++)
#pragma unroll
                for (int r = 0; r < 4; r++) {
                    const int gm = bm + wm + mt * 16 + quad * 4 + r;
                    const int gn = bn + wn + nt * 16 + l16;
                    Qb[(size_t)gm * DIM + gn] = (bf16_t)acc[mt][nt][r];
                }
    } else if (bn < 2 * DIM) {
#pragma unroll
        for (int mt = 0; mt < 4; mt++)
#pragma unroll
            for (int nt = 0; nt < NT; nt++)
#pragma unroll
                for (int r = 0; r < 4; r++) {
                    const int gm = bm + wm + mt * 16 + quad * 4 + r;
                    const int gn = bn + wn + nt * 16 + l16 - DIM;
                    Kb[(size_t)gm * DIM + gn] = (bf16_t)acc[mt][nt][r];
                }
    } else {
        // V^T: transpose through LDS, then KV-PERMUTED coalesced 16B stores
        bf16_t* tr = smem;
#pragma unroll
        for (int mt = 0; mt < 4; mt++)
#pragma unroll
            for (int nt = 0; nt < NT; nt++) {
                bf16x4 tv;
#pragma unroll
                for (int r = 0; r < 4; r++) tv[r] = (bf16_t)acc[mt][nt][r];
                *(bf16x4*)(&tr[(wn + nt * 16 + l16) * 136 + wm + mt * 16 + quad * 4]) = tv;
            }
        __syncthreads();
        const int b = bm >> 11, kv0 = bm & 2047;
        const int n2base = bn - 2 * DIM;
        const int cg = tid & 15, cc = cg >> 2, cq = cg & 3;
#pragma unroll
        for (int i = 0; i < TN / 16; i++) {
            const int row = i * 16 + (tid >> 4);
            const int n2 = n2base + row, h = n2 >> 6, d = n2 & 63;
            const bf16x4 lo4 = *(const bf16x4*)(&tr[row * 136 + cc * 32 + cq * 4]);
            const bf16x4 hi4 = *(const bf16x4*)(&tr[row * 136 + cc * 32 + 16 + cq * 4]);
            bf16x8 vv;
#pragma unroll
            for (int j = 0; j < 4; j++) { vv[j] = lo4[j]; vv[4 + j] = hi4[j]; }
            *(bf16x8*)(Vtb + ((size_t)(b * HEADS + h) * HD + d) * NKV + kv0 + cg * 8) = vv;
        }
    }
}

// ---------------- flash attention: kv-quarter waves = 1x LDS traffic, KVBLK=128 dbuf ------
// grid (NB*HEADS, NQ/64) = 768 blocks. 4 waves; wave w owns kv rows [w*32,w*32+32) of each
// 128-tile x ALL 64 q-rows. ROUND-5 POST-MORTEM: old decomposition (16 q/wave) made every
// wave read the whole tile -> 1 b128 per MFMA -> ~21us of pure LDS-read serialization/CU.
// Here each tile byte is read ONCE per block (kf/vf b128 each feed 4 MFMA; 4x less LDS
// traffic). Per-wave partial O/li over its quarter, merged once in a 2-phase LDS tree.
// dbuf 64KB -> 2 blocks/CU (OK now: LDS pressure is 4x lower; per-tile compute ~600cy
// covers L2 latency of the prefetch issued a full phase ahead). Producer V-permutation:
// group cc = wave (same algebra as old kc), XOR bank-unswizzle unchanged. T5 setprio kept.
__global__ __launch_bounds__(256, 2)
void attn_kernel(const bf16_t* __restrict__ Qb, const bf16_t* __restrict__ Kb,
                 const bf16_t* __restrict__ Vt, bf16_t* __restrict__ Xb)
{
    __shared__ __align__(16) bf16_t kvbuf[2][16384]; // per buf: K[128][64]:[0,8192) V^T[64][128]:[8192,16384)
    __shared__ float libuf[4][4][16];

    const int tid  = threadIdx.x;
    const int wave = tid >> 6, lane = tid & 63;
    const int quad = lane >> 4, l16 = lane & 15;
    const int l7   = l16 & 7;

    // XCD-locality swizzle (bijective on 768 = 8 XCDs x 3 heads x 32 q-tiles)
    const int id   = blockIdx.x + (NB * HEADS) * blockIdx.y;
    const int xcd  = id & 7, slot = id >> 3;
    const int bh   = xcd + 8 * (slot >> 5);
    const int b = bh / HEADS, h = bh % HEADS;
    const int q0 = (slot & 31) * 64;

    const bf16_t* Qp = Qb + (size_t)b * NQ * DIM + h * HD;
    const bf16_t* Kp = Kb + (size_t)b * NKV * DIM + h * HD;
    const bf16_t* Vp = Vt + (size_t)(b * HEADS + h) * HD * NKV;

    // staging bases. K: 256 threads = 32 rows x 8 chunks, 4 copies cover 128 rows.
    // phys LDS chunk sp of row r holds global chunk sp^(r&7) (bank XOR folded into global addr)
    const int ksr = tid >> 3, ksp = tid & 7;
    const bf16_t* KgA = Kp + (size_t)ksr * DIM + ((ksp ^ (ksr & 7)) * 8);
    // V^T: 256 threads = 16 d-rows x 16 chunks, 4 copies cover 64 d-rows.
    const int vsd = tid >> 4, vsp = tid & 15;
    const bf16_t* VgA = Vp + (size_t)vsd * NKV + ((vsp ^ (vsd & 7)) * 8);

    // prologue: stage tile 0 into buf 0 (before Q-frag loads so both overlap)
    {
        bf16_t* kb = kvbuf[0] + tid * 8;
        bf16_t* vb = kvbuf[0] + 8192 + tid * 8;
#pragma unroll
        for (int i = 0; i < 4; i++) async_copy16(KgA + (size_t)(i * 32) * DIM, kb + i * 2048);
#pragma unroll
        for (int i = 0; i < 4; i++) async_copy16(VgA + (size_t)(i * 16) * NKV, vb + i * 2048);
    }

    // Q B-frags (reg-resident, pre-scaled): q = q0 + qt*16 + l16, k(d) = ks*32 + quad*8 + j
    bf16x8 qf[4][2];
#pragma unroll
    for (int qt = 0; qt < 4; qt++)
#pragma unroll
        for (int ks = 0; ks < 2; ks++)
            qf[qt][ks] = *(const bf16x8*)(Qp + (size_t)(q0 + qt * 16 + l16) * DIM
                                          + ks * 32 + quad * 8);

    f32x4 o[4][4] = {};                   // [dt][qt], wave's kv-quarter partial
    float li[4] = {0.0f, 0.0f, 0.0f, 0.0f};

    __syncthreads();   // tile 0 staged

    for (int t = 0; t < NKV / 128; t++) {
        const bf16_t* kv = kvbuf[t & 1];

        // prefetch next tile into the other buffer (drained by the barrier BELOW)
        if (t + 1 < NKV / 128) {
            bf16_t* kb = kvbuf[(t + 1) & 1] + tid * 8;
            bf16_t* vb = kvbuf[(t + 1) & 1] + 8192 + tid * 8;
            const int kv1 = (t + 1) * 128;
#pragma unroll
            for (int i = 0; i < 4; i++)
                async_copy16(KgA + (size_t)(kv1 + i * 32) * DIM, kb + i * 2048);
#pragma unroll
            for (int i = 0; i < 4; i++)
                async_copy16(VgA + (size_t)(i * 16) * NKV + kv1, vb + i * 2048);
        }

        // S^T = K @ Q^T : lane holds S^T[kv = wave*32 + kt*16 + quad*4 + r][q = qt*16 + l16]
        f32x4 s[2][4] = {};
        __builtin_amdgcn_s_setprio(1);
#pragma unroll
        for (int kt = 0; kt < 2; kt++)
#pragma unroll
            for (int ks = 0; ks < 2; ks++) {
                const bf16x8 kf = *(const bf16x8*)(&kv[
                    (wave * 32 + kt * 16 + l16) * 64 + (((ks * 4 + quad) ^ l7) * 8)]);
#pragma unroll
                for (int qt = 0; qt < 4; qt++)
                    s[kt][qt] = __builtin_amdgcn_mfma_f32_16x16x32_bf16(
                        kf, qf[qt][ks], s[kt][qt], 0, 0, 0);
            }
        __builtin_amdgcn_s_setprio(0);

        // softmax (no max-subtraction; scale folded in Wq) + pack PV B-frags
        // j-order matches producer V-permutation: kv = wave*32 + (j>>2)*16 + quad*4 + (j&3)
        bf16x8 pb[4];
#pragma unroll
        for (int qt = 0; qt < 4; qt++) {
            float pj[8];
#pragma unroll
            for (int kt = 0; kt < 2; kt++)
#pragma unroll
                for (int r = 0; r < 4; r++) pj[kt * 4 + r] = fast_exp2(s[kt][qt][r]);
            float rs = 0.0f;
#pragma unroll
            for (int j = 0; j < 8; j++) rs += pj[j];
            li[qt] += rs;
            bf16x8 t8;
#pragma unroll
            for (int j = 0; j < 8; j++) t8[j] = (bf16_t)pj[j];
            pb[qt] = t8;
        }

        // O^T += V^T @ P^T over this wave's 32-kv quarter (single k-step)
        __builtin_amdgcn_s_setprio(1);
#pragma unroll
        for (int dt = 0; dt < 4; dt++) {
            const bf16x8 vf = *(const bf16x8*)(&kv[
                8192 + (dt * 16 + l16) * 128 + (((wave * 4 + quad) ^ l7) * 8)]);
#pragma unroll
            for (int qt = 0; qt < 4; qt++)
                o[dt][qt] = __builtin_amdgcn_mfma_f32_16x16x32_bf16(
                    vf, pb[qt], o[dt][qt], 0, 0, 0);
        }
        __builtin_amdgcn_s_setprio(0);

        // single barrier per tile: drains the prefetch and fences reads of buf(t)
        __syncthreads();
    }

    // per-wave li: reduce across quads (quads covered disjoint kv rows of the quarter)
#pragma unroll
    for (int qt = 0; qt < 4; qt++) {
        li[qt] += __shfl_xor(li[qt], 16);
        li[qt] += __shfl_xor(li[qt], 32);
    }
    if (quad == 0)
#pragma unroll
        for (int qt = 0; qt < 4; qt++) libuf[wave][qt][l16] = li[qt];

    // 2-phase tree merge of the 4 kv-quarter partials (kvbuf reused; [64 d][66 q] f32 regions)
    float* R = (float*)&kvbuf[0][0];
    const int rr = quad * 4;
    if (wave >= 2) {
        float* Rw = R + (size_t)(wave - 2) * (64 * 66);
#pragma unroll
        for (int dt = 0; dt < 4; dt++)
#pragma unroll
            for (int qt = 0; qt < 4; qt++)
#pragma unroll
                for (int r = 0; r < 4; r++)
                    Rw[(dt * 16 + rr + r) * 66 + qt * 16 + l16] = o[dt][qt][r];
    }
    __syncthreads();
    if (wave < 2) {
        float* Rw = R + (size_t)wave * (64 * 66);
#pragma unroll
        for (int dt = 0; dt < 4; dt++)
#pragma unroll
            for (int qt = 0; qt < 4; qt++)
#pragma unroll
                for (int r = 0; r < 4; r++)
                    o[dt][qt][r] += Rw[(dt * 16 + rr + r) * 66 + qt * 16 + l16];
    }
    __syncthreads();
    if (wave == 1) {
#pragma unroll
        for (int dt = 0; dt < 4; dt++)
#pragma unroll
            for (int qt = 0; qt < 4; qt++)
#pragma unroll
                for (int r = 0; r < 4; r++)
                    R[(dt * 16 + rr + r) * 66 + qt * 16 + l16] = o[dt][qt][r];
    }
    __syncthreads();
    bf16_t* Ob16 = (bf16_t*)(R + 2 * 64 * 66);   // [64 q][72 d] = 9216 B, no alias with R0
    if (wave == 0) {
        float inv[4];
#pragma unroll
        for (int qt = 0; qt < 4; qt++)
            inv[qt] = 1.0f / (libuf[0][qt][l16] + libuf[1][qt][l16]
                              + libuf[2][qt][l16] + libuf[3][qt][l16]);
#pragma unroll
        for (int dt = 0; dt < 4; dt++)
#pragma unroll
            for (int qt = 0; qt < 4; qt++) {
                bf16x4 ov;
#pragma unroll
                for (int r = 0; r < 4; r++)
                    ov[r] = (bf16_t)((o[dt][qt][r]
                                      + R[(dt * 16 + rr + r) * 66 + qt * 16 + l16]) * inv[qt]);
                *(bf16x4*)(&Ob16[(qt * 16 + l16) * 72 + dt * 16 + rr]) = ov;
            }
    }
    __syncthreads();
    {
        const int row = tid >> 2, ch = (tid & 3) * 16;
        bf16_t* dst = Xb + (size_t)(b * NQ + q0 + row) * DIM + h * HD + ch;
        *(bf16x8*)(dst)     = *(const bf16x8*)(&Ob16[row * 72 + ch]);
        *(bf16x8*)(dst + 8) = *(const bf16x8*)(&Ob16[row * 72 + ch + 8]);
    }
}

extern "C" void kernel_launch(void* const* d_in, const int* in_sizes, int n_in,
                              void* d_out, int out_size, void* d_ws, size_t ws_size,
                              hipStream_t stream)
{
    const float* qs    = (const float*)d_in[0];
    const float* kvs   = (const float*)d_in[1];
    const float* Wq    = (const float*)d_in[2];
    const float* Wkv   = (const float*)d_in[3];
    const float* Wproj = (const float*)d_in[4];
    const float* bproj = (const float*)d_in[5];
    float* out = (float*)d_out;

    bf16_t* w = (bf16_t*)d_ws;
    bf16_t* qs_bf  = w;  w += (size_t)MROWS * DIM;
    bf16_t* kvs_bf = w;  w += (size_t)MROWS * DIM;
    bf16_t* Wt     = w;  w += (size_t)NQKV * DIM;   // Wqt | Wkvt contiguous
    bf16_t* Wprojt = w;  w += (size_t)DIM * DIM;
    bf16_t* Qb     = w;  w += (size_t)MROWS * DIM;
    bf16_t* Kb     = w;  w += (size_t)MROWS * DIM;
    bf16_t* Vtb    = w;  w += (size_t)MROWS * DIM;
    bf16_t* Xb     = qs_bf;   // qs_bf dead after QKV GEMM

    const float escale = 0.125f * 1.44269504088896341f;  // Dh^-0.5 * log2(e), folded into Wq
    prep_kernel<<<dim3(MROWS * DIM / 2048, 1, 5), 256, 0, stream>>>(
        qs, qs_bf, kvs, kvs_bf, Wq, Wkv, Wproj, Wt, escale);

    // 128x96 tile: grid 32x24 = 768 blocks (2 resident/CU + refill; balanced work = 3/CU)
    gemm_bk64<0, 96><<<dim3(MROWS / 128, NQKV / 96), 256, 0, stream>>>(
        qs_bf, kvs_bf, Wt, Qb, Kb, Vtb, nullptr, nullptr);
    attn_kernel<<<dim3(NB * HEADS, NQ / 64), 256, 0, stream>>>(Qb, Kb, Vtb, Xb);
    // 128x32 tile: grid 32x24 = 768 blocks; dbuf LDS 40KB keeps 4 blocks/CU
    gemm_bk64<1, 32><<<dim3(MROWS / 128, DIM / 32), 256, 0, stream>>>(
        Xb, nullptr, Wprojt, nullptr, nullptr, nullptr, out, bproj);
}

// Round 7
// 152.481 us; speedup vs baseline: 1.0721x; 1.0721x over previous
//
#include <hip/hip_runtime.h>
#include <math.h>
#include <stdint.h>

typedef __bf16 bf16_t;
typedef __attribute__((ext_vector_type(8))) __bf16 bf16x8;
typedef __attribute__((ext_vector_type(4))) __bf16 bf16x4;
typedef __attribute__((ext_vector_type(4))) float f32x4;

#define DIM   768
#define HEADS 12
#define HD    64
#define NB    2
#define NQ    2048
#define NKV   2048
#define MROWS 4096
#define NQKV  2304   /* DIM(Q) + 2*DIM(KV) */

// ---- compile-safe fast exp2 (single v_exp_f32 when builtin exists) ----
__device__ __forceinline__ float fast_exp2(float x)
{
#if __has_builtin(__builtin_amdgcn_exp2f)
    return __builtin_amdgcn_exp2f(x);
#else
    return exp2f(x);
#endif
}

// async 16B global -> LDS (m97 trick). LDS dest must be uniform + lane*16.
__device__ __forceinline__ void async_copy16(const bf16_t* g, bf16_t* l)
{
    typedef const __attribute__((address_space(1))) uint32_t* gp_t;
    typedef __attribute__((address_space(3))) uint32_t* lp_t;
    __builtin_amdgcn_global_load_lds((gp_t)(const void*)g, (lp_t)(void*)l, 16, 0, 0);
}

// ---------------- fused prep: casts (z=0,1) + weight transposes (z=2,3,4) ----------------
__global__ void prep_kernel(const float* __restrict__ qs, bf16_t* __restrict__ qs_bf,
                            const float* __restrict__ kvs, bf16_t* __restrict__ kvs_bf,
                            const float* __restrict__ Wq, const float* __restrict__ Wkv,
                            const float* __restrict__ Wproj, bf16_t* __restrict__ Wt,
                            float escale)
{
    __shared__ float tile[32][33];
    const int z = blockIdx.z;
    if (z < 2) {
        const float* in  = z ? kvs : qs;
        bf16_t*      out = z ? kvs_bf : qs_bf;
        const int i = (blockIdx.x * 256 + threadIdx.x) * 8;   // grid.x*2048 == MROWS*DIM
        bf16x8 v;
#pragma unroll
        for (int j = 0; j < 8; j++) v[j] = (bf16_t)in[i + j];
        *(bf16x8*)(out + i) = v;
        return;
    }
    const int N   = (z == 3) ? 2 * DIM : DIM;
    const int nb  = N / 32;
    const int idx = blockIdx.x;
    if (idx >= nb * (DIM / 32)) return;
    const float* W = (z == 2) ? Wq : (z == 3) ? Wkv : Wproj;
    bf16_t* T = Wt + ((z == 2) ? (size_t)0 : (z == 3) ? (size_t)DIM * DIM
                                                      : (size_t)NQKV * DIM);
    const float scl = (z == 2) ? escale : 1.0f;
    const int n0 = (idx % nb) * 32, k0 = (idx / nb) * 32;
    const int tx = threadIdx.x & 31, ty = threadIdx.x >> 5;
#pragma unroll
    for (int i = 0; i < 4; i++)
        tile[ty + i * 8][tx] = W[(size_t)(k0 + ty + i * 8) * N + n0 + tx];
    __syncthreads();
#pragma unroll
    for (int i = 0; i < 4; i++)
        T[(size_t)(n0 + ty + i * 8) * DIM + k0 + tx] = (bf16_t)(tile[tx][ty + i * 8] * scl);
}

// ---------------- GEMM: 128xTN tile, BK=64, T3 2-phase double-buffered staging --------
// MODE 0: fused QKV (N=2304). Q (pre-scaled via Wq) / K stored plain [b,tok,768];
//         V^T stored KV-PERMUTED so attn's PV A-frags are single contiguous b128.
// MODE 1: proj (fp32 out + bias)
// Round-4 verified: 2-phase dbuf (stage(t+1) before compute(t), ONE barrier/step) -4.4us.
template<int MODE, int TN>
__global__ __launch_bounds__(256)
void gemm_bk64(const bf16_t* __restrict__ Aq, const bf16_t* __restrict__ Akv,
               const bf16_t* __restrict__ Bt,
               bf16_t* __restrict__ Qb, bf16_t* __restrict__ Kb, bf16_t* __restrict__ Vtb,
               float* __restrict__ ofp, const float* __restrict__ bias)
{
    constexpr int K  = DIM;
    constexpr int NT = TN / 32;
    constexpr int ABLK = 128 * 64;
    constexpr int BBLK = TN * 64;
    constexpr int STEP = ABLK + BBLK;                      // one staging buffer
    constexpr int TRELEMS = (MODE == 0) ? 128 * 136 : 0;   // V-transpose epilogue scratch
    constexpr int SELEMS = (2 * STEP > TRELEMS) ? 2 * STEP : TRELEMS;
    __shared__ __align__(16) bf16_t smem[SELEMS];

    const int tid  = threadIdx.x;
    const int wave = tid >> 6, lane = tid & 63;
    const int quad = lane >> 4, l16 = lane & 15, l7 = l16 & 7;
    const int bm = blockIdx.x * 128, bn = blockIdx.y * TN;
    const int wm = (wave >> 1) * 64, wn = (wave & 1) * (TN / 2);

    const bf16_t* A = (MODE == 0) ? (bn < DIM ? Aq : Akv) : Aq;

    const int srow = tid >> 3;
    const int scol = ((tid & 7) ^ (srow & 7)) * 8;
    const bf16_t* Ag[4];
    const bf16_t* Bg[NT];
#pragma unroll
    for (int i = 0; i < 4; i++)
        Ag[i] = A + (size_t)(bm + i * 32 + srow) * K + scol;
#pragma unroll
    for (int i = 0; i < NT; i++)
        Bg[i] = Bt + (size_t)(bn + i * 32 + srow) * K + scol;

    f32x4 acc[4][NT] = {};

    // prologue: stage K-step 0 into buf 0
    {
        bf16_t* AsL = smem + tid * 8;
        bf16_t* BsL = smem + ABLK + tid * 8;
#pragma unroll
        for (int i = 0; i < 4; i++) async_copy16(Ag[i], AsL + i * 2048);
#pragma unroll
        for (int i = 0; i < NT; i++) async_copy16(Bg[i], BsL + i * 2048);
    }
    __syncthreads();

    for (int t = 0; t < K / 64; t++) {
        bf16_t* Ac = smem + (t & 1) * STEP;
        bf16_t* Bc = Ac + ABLK;

        // prefetch next K-step into the other buffer (latency hides under compute)
        if (t + 1 < K / 64) {
            bf16_t* AsL = smem + ((t + 1) & 1) * STEP + tid * 8;
            bf16_t* BsL = AsL + ABLK;
            const int k1 = (t + 1) * 64;
#pragma unroll
            for (int i = 0; i < 4; i++) async_copy16(Ag[i] + k1, AsL + i * 2048);
#pragma unroll
            for (int i = 0; i < NT; i++) async_copy16(Bg[i] + k1, BsL + i * 2048);
        }

#pragma unroll
        for (int ks = 0; ks < 2; ks++) {
            const int pc = ((ks * 4 + quad) ^ l7) * 8;
            bf16x8 af[4], bfr[NT];
#pragma unroll
            for (int mt = 0; mt < 4; mt++)
                af[mt] = *(const bf16x8*)(&Ac[(wm + mt * 16 + l16) * 64 + pc]);
#pragma unroll
            for (int nt = 0; nt < NT; nt++)
                bfr[nt] = *(const bf16x8*)(&Bc[(wn + nt * 16 + l16) * 64 + pc]);
#pragma unroll
            for (int mt = 0; mt < 4; mt++)
#pragma unroll
                for (int nt = 0; nt < NT; nt++)
                    acc[mt][nt] = __builtin_amdgcn_mfma_f32_16x16x32_bf16(
                        af[mt], bfr[nt], acc[mt][nt], 0, 0, 0);
        }

        // single barrier per K-step: drains the prefetch (issued a compute-phase ago)
        // and fences reads of buf(t) before iteration t+1's prefetch overwrites it
        __syncthreads();
    }

    // ---- epilogue; C layout: col = lane&15, row = quad*4 + reg ----
    if (MODE == 1) {
#pragma unroll
        for (int mt = 0; mt < 4; mt++)
#pragma unroll
            for (int nt = 0; nt < NT; nt++)
#pragma unroll
                for (int r = 0; r < 4; r++) {
                    const int gm = bm + wm + mt * 16 + quad * 4 + r;
                    const int gn = bn + wn + nt * 16 + l16;
                    ofp[(size_t)gm * DIM + gn] = acc[mt][nt][r] + bias[gn];
                }
    } else if (bn < DIM) {
#pragma unroll
        for (int mt = 0; mt < 4; mt++)
#pragma unroll
            for (int nt = 0; nt < NT; nt++)
#pragma unroll
                for (int r = 0; r < 4; r++) {
                    const int gm = bm + wm + mt * 16 + quad * 4 + r;
                    const int gn = bn + wn + nt * 16 + l16;
                    Qb[(size_t)gm * DIM + gn] = (bf16_t)acc[mt][nt][r];
                }
    } else if (bn < 2 * DIM) {
#pragma unroll
        for (int mt = 0; mt < 4; mt++)
#pragma unroll
            for (int nt = 0; nt < NT; nt++)
#pragma unroll
                for (int r = 0; r < 4; r++) {
                    const int gm = bm + wm + mt * 16 + quad * 4 + r;
                    const int gn = bn + wn + nt * 16 + l16 - DIM;
                    Kb[(size_t)gm * DIM + gn] = (bf16_t)acc[mt][nt][r];
                }
    } else {
        // V^T: transpose through LDS, then KV-PERMUTED coalesced 16B stores
        bf16_t* tr = smem;
#pragma unroll
        for (int mt = 0; mt < 4; mt++)
#pragma unroll
            for (int nt = 0; nt < NT; nt++) {
                bf16x4 tv;
#pragma unroll
                for (int r = 0; r < 4; r++) tv[r] = (bf16_t)acc[mt][nt][r];
                *(bf16x4*)(&tr[(wn + nt * 16 + l16) * 136 + wm + mt * 16 + quad * 4]) = tv;
            }
        __syncthreads();
        const int b = bm >> 11, kv0 = bm & 2047;
        const int n2base = bn - 2 * DIM;
        const int cg = tid & 15, cc = cg >> 2, cq = cg & 3;
#pragma unroll
        for (int i = 0; i < TN / 16; i++) {
            const int row = i * 16 + (tid >> 4);
            const int n2 = n2base + row, h = n2 >> 6, d = n2 & 63;
            const bf16x4 lo4 = *(const bf16x4*)(&tr[row * 136 + cc * 32 + cq * 4]);
            const bf16x4 hi4 = *(const bf16x4*)(&tr[row * 136 + cc * 32 + 16 + cq * 4]);
            bf16x8 vv;
#pragma unroll
            for (int j = 0; j < 4; j++) { vv[j] = lo4[j]; vv[4 + j] = hi4[j]; }
            *(bf16x8*)(Vtb + ((size_t)(b * HEADS + h) * HD + d) * NKV + kv0 + cg * 8) = vv;
        }
    }
}

// ---------------- flash attention: 8-wave blocks, 24 waves/CU, KVBLK=64 single-buffer ------
// ROUNDS 1-6 EMPIRICAL LAW: attn time x resident-blocks ~= const (54.6x2 ~ 38.6x3) across
// widely varying LDS traffic / dbuf structures -> pure concurrency-bound. Fix: same grid
// (768 = 3 blocks/CU) but 512-thread 8-wave blocks -> 24 waves/CU (was 12), while q-tile
// stays 64 so KV L2 re-read stays 393MB (~11us L2 floor). Wave (qh 0..3, kvh 0..1) owns
// 16 q x 32 kv of each 64-kv tile. Single-buffer 16KB staging (stage;bar;compute;bar).
// kv-half merge: 2-phase in-LDS f32 tree (R [64][33]), then bf16 [64][72] cooperative store.
// launch_bounds(512,6) caps VGPR ~85 -> 6 waves/SIMD. T5 setprio kept.
__global__ __launch_bounds__(512, 6)
void attn_kernel(const bf16_t* __restrict__ Qb, const bf16_t* __restrict__ Kb,
                 const bf16_t* __restrict__ Vt, bf16_t* __restrict__ Xb)
{
    // staging: K[64][64] at [0,4096), V^T[64][64] at [4096,8192) (16KB)
    // epilogue reuse: R f32[64][33] at byte 0; Ob16 [64 q][72 d] bf16 at elem 4224
    __shared__ __align__(16) bf16_t kvbuf[8960];
    __shared__ float libuf[4][16];

    const int tid  = threadIdx.x;
    const int wave = tid >> 6, lane = tid & 63;
    const int quad = lane >> 4, l16 = lane & 15;
    const int l7   = l16 & 7;
    const int kvh = wave & 1, qh = wave >> 1;   // qh 0..3, kvh 0..1

    // XCD-locality swizzle (bijective on 768 = 8 XCDs x 3 heads x 32 q-tiles)
    const int id   = blockIdx.x;
    const int xcd  = id & 7, slot = id >> 3;
    const int bh   = xcd + 8 * (slot >> 5);
    const int b = bh / HEADS, h = bh % HEADS;
    const int q0 = (slot & 31) * 64;

    const bf16_t* Qp = Qb + (size_t)b * NQ * DIM + h * HD;
    const bf16_t* Kp = Kb + (size_t)b * NKV * DIM + h * HD;
    const bf16_t* Vp = Vt + (size_t)(b * HEADS + h) * HD * NKV;

    // staging bases: 512 threads = 64 rows x 8 chunks, one async_copy16 each for K and V.
    // phys LDS chunk sp of row r holds logical chunk sp^(r&7) (bank XOR folded into global
    // addr). Producer V-permutation is LINEAR at 8-chunk granularity (verified r5/r6), so
    // chunk cl of the 64-kv tile sits at global kv0 + cl*8.
    const int sr = tid >> 3, sp = tid & 7;
    const bf16_t* KgA = Kp + (size_t)sr * DIM + ((sp ^ (sr & 7)) * 8);
    const bf16_t* VgA = Vp + (size_t)sr * NKV + ((sp ^ (sr & 7)) * 8);

    // Q B-frags (reg-resident, pre-scaled): q = q0 + qh*16 + l16, k(d) = ks*32 + quad*8 + j
    bf16x8 qf[2];
#pragma unroll
    for (int ks = 0; ks < 2; ks++)
        qf[ks] = *(const bf16x8*)(Qp + (size_t)(q0 + qh * 16 + l16) * DIM
                                  + ks * 32 + quad * 8);

    f32x4 o[4] = {};
    float li = 0.0f;

    for (int t = 0; t < NKV / 64; t++) {
        const int kv0 = t * 64;
        async_copy16(KgA + (size_t)kv0 * DIM, kvbuf + tid * 8);
        async_copy16(VgA + kv0, kvbuf + 4096 + tid * 8);
        __syncthreads();

        // S^T = K @ Q^T : lane holds S^T[kv = kvh*32 + kt*16 + quad*4 + r][q = l16]
        f32x4 s[2] = {};
        __builtin_amdgcn_s_setprio(1);
#pragma unroll
        for (int kt = 0; kt < 2; kt++)
#pragma unroll
            for (int ks = 0; ks < 2; ks++) {
                const bf16x8 kf = *(const bf16x8*)(&kvbuf[
                    (kvh * 32 + kt * 16 + l16) * 64 + (((ks * 4 + quad) ^ l7) * 8)]);
                s[kt] = __builtin_amdgcn_mfma_f32_16x16x32_bf16(kf, qf[ks], s[kt], 0, 0, 0);
            }
        __builtin_amdgcn_s_setprio(0);

        // softmax (no max-subtraction; scale folded in Wq) + pack PV B-frag
        // p[j]: kv = kvh*32 + (j>>2)*16 + quad*4 + (j&3) — matches producer V j-order
        float p[8];
#pragma unroll
        for (int kt = 0; kt < 2; kt++)
#pragma unroll
            for (int r = 0; r < 4; r++) p[kt * 4 + r] = fast_exp2(s[kt][r]);
        float rs = 0.0f;
#pragma unroll
        for (int j = 0; j < 8; j++) rs += p[j];
        li += rs;
        bf16x8 pb;
#pragma unroll
        for (int j = 0; j < 8; j++) pb[j] = (bf16_t)p[j];

        // O^T += V^T @ P^T over this wave's 32-kv half (single k-step)
        __builtin_amdgcn_s_setprio(1);
#pragma unroll
        for (int dt = 0; dt < 4; dt++) {
            const bf16x8 vf = *(const bf16x8*)(&kvbuf[
                4096 + (dt * 16 + l16) * 64 + (((kvh * 4 + quad) ^ l7) * 8)]);
            o[dt] = __builtin_amdgcn_mfma_f32_16x16x32_bf16(vf, pb, o[dt], 0, 0, 0);
        }
        __builtin_amdgcn_s_setprio(0);
        __syncthreads();
    }

    // li: reduce across quads (quads covered disjoint kv rows of the half)
    li += __shfl_xor(li, 16);
    li += __shfl_xor(li, 32);
    if (kvh == 1 && quad == 0) libuf[qh][l16] = li;

    // 2-phase kv-half merge: R f32[64 d][33] (8.4KB), Ob16 [64 q][72 d] at elem 4224
    float*  R    = (float*)&kvbuf[0];
    bf16_t* Ob16 = kvbuf + 4224;
#pragma unroll
    for (int ph = 0; ph < 2; ph++) {
        if (kvh == 1 && (qh >> 1) == ph) {
#pragma unroll
            for (int dt = 0; dt < 4; dt++)
#pragma unroll
                for (int r = 0; r < 4; r++)
                    R[(dt * 16 + quad * 4 + r) * 33 + (qh & 1) * 16 + l16] = o[dt][r];
        }
        __syncthreads();
        if (kvh == 0 && (qh >> 1) == ph) {
            const float inv = 1.0f / (li + libuf[qh][l16]);
#pragma unroll
            for (int dt = 0; dt < 4; dt++) {
                bf16x4 ov;
#pragma unroll
                for (int r = 0; r < 4; r++)
                    ov[r] = (bf16_t)((o[dt][r]
                                      + R[(dt * 16 + quad * 4 + r) * 33 + (qh & 1) * 16 + l16])
                                     * inv);
                *(bf16x4*)(&Ob16[(qh * 16 + l16) * 72 + dt * 16 + quad * 4]) = ov;
            }
        }
        __syncthreads();
    }
    {
        const int row = tid >> 3, ch = (tid & 7) * 8;
        bf16_t* dst = Xb + (size_t)(b * NQ + q0 + row) * DIM + h * HD + ch;
        *(bf16x8*)(dst) = *(const bf16x8*)(&Ob16[row * 72 + ch]);
    }
}

extern "C" void kernel_launch(void* const* d_in, const int* in_sizes, int n_in,
                              void* d_out, int out_size, void* d_ws, size_t ws_size,
                              hipStream_t stream)
{
    const float* qs    = (const float*)d_in[0];
    const float* kvs   = (const float*)d_in[1];
    const float* Wq    = (const float*)d_in[2];
    const float* Wkv   = (const float*)d_in[3];
    const float* Wproj = (const float*)d_in[4];
    const float* bproj = (const float*)d_in[5];
    float* out = (float*)d_out;

    bf16_t* w = (bf16_t*)d_ws;
    bf16_t* qs_bf  = w;  w += (size_t)MROWS * DIM;
    bf16_t* kvs_bf = w;  w += (size_t)MROWS * DIM;
    bf16_t* Wt     = w;  w += (size_t)NQKV * DIM;   // Wqt | Wkvt contiguous
    bf16_t* Wprojt = w;  w += (size_t)DIM * DIM;
    bf16_t* Qb     = w;  w += (size_t)MROWS * DIM;
    bf16_t* Kb     = w;  w += (size_t)MROWS * DIM;
    bf16_t* Vtb    = w;  w += (size_t)MROWS * DIM;
    bf16_t* Xb     = qs_bf;   // qs_bf dead after QKV GEMM

    const float escale = 0.125f * 1.44269504088896341f;  // Dh^-0.5 * log2(e), folded into Wq
    prep_kernel<<<dim3(MROWS * DIM / 2048, 1, 5), 256, 0, stream>>>(
        qs, qs_bf, kvs, kvs_bf, Wq, Wkv, Wproj, Wt, escale);

    // 128x96 tile: grid 32x24 = 768 blocks (2 resident/CU + refill; balanced work = 3/CU)
    gemm_bk64<0, 96><<<dim3(MROWS / 128, NQKV / 96), 256, 0, stream>>>(
        qs_bf, kvs_bf, Wt, Qb, Kb, Vtb, nullptr, nullptr);
    // 768 blocks x 512 threads = 3 blocks/CU x 8 waves = 24 waves/CU
    attn_kernel<<<dim3(768), 512, 0, stream>>>(Qb, Kb, Vtb, Xb);
    // 128x32 tile: grid 32x24 = 768 blocks; dbuf LDS 40KB keeps 4 blocks/CU
    gemm_bk64<1, 32><<<dim3(MROWS / 128, DIM / 32), 256, 0, stream>>>(
        Xb, nullptr, Wprojt, nullptr, nullptr, nullptr, out, bproj);
}

// Round 8
// 151.631 us; speedup vs baseline: 1.0782x; 1.0056x over previous
//
#include <hip/hip_runtime.h>
#include <math.h>
#include <stdint.h>

typedef __bf16 bf16_t;
typedef __attribute__((ext_vector_type(8))) __bf16 bf16x8;
typedef __attribute__((ext_vector_type(4))) __bf16 bf16x4;
typedef __attribute__((ext_vector_type(4))) float f32x4;

#define DIM   768
#define HEADS 12
#define HD    64
#define NB    2
#define NQ    2048
#define NKV   2048
#define MROWS 4096
#define NQKV  2304   /* DIM(Q) + 2*DIM(KV) */

// ---- compile-safe fast exp2 (single v_exp_f32 when builtin exists) ----
__device__ __forceinline__ float fast_exp2(float x)
{
#if __has_builtin(__builtin_amdgcn_exp2f)
    return __builtin_amdgcn_exp2f(x);
#else
    return exp2f(x);
#endif
}

// async 16B global -> LDS (m97 trick). LDS dest must be uniform + lane*16.
__device__ __forceinline__ void async_copy16(const bf16_t* g, bf16_t* l)
{
    typedef const __attribute__((address_space(1))) uint32_t* gp_t;
    typedef __attribute__((address_space(3))) uint32_t* lp_t;
    __builtin_amdgcn_global_load_lds((gp_t)(const void*)g, (lp_t)(void*)l, 16, 0, 0);
}

// ---------------- fused prep: casts (z=0,1) + weight transposes (z=2,3,4) ----------------
__global__ void prep_kernel(const float* __restrict__ qs, bf16_t* __restrict__ qs_bf,
                            const float* __restrict__ kvs, bf16_t* __restrict__ kvs_bf,
                            const float* __restrict__ Wq, const float* __restrict__ Wkv,
                            const float* __restrict__ Wproj, bf16_t* __restrict__ Wt,
                            float escale)
{
    __shared__ float tile[32][33];
    const int z = blockIdx.z;
    if (z < 2) {
        const float* in  = z ? kvs : qs;
        bf16_t*      out = z ? kvs_bf : qs_bf;
        const int i = (blockIdx.x * 256 + threadIdx.x) * 8;   // grid.x*2048 == MROWS*DIM
        bf16x8 v;
#pragma unroll
        for (int j = 0; j < 8; j++) v[j] = (bf16_t)in[i + j];
        *(bf16x8*)(out + i) = v;
        return;
    }
    const int N   = (z == 3) ? 2 * DIM : DIM;
    const int nb  = N / 32;
    const int idx = blockIdx.x;
    if (idx >= nb * (DIM / 32)) return;
    const float* W = (z == 2) ? Wq : (z == 3) ? Wkv : Wproj;
    bf16_t* T = Wt + ((z == 2) ? (size_t)0 : (z == 3) ? (size_t)DIM * DIM
                                                      : (size_t)NQKV * DIM);
    const float scl = (z == 2) ? escale : 1.0f;
    const int n0 = (idx % nb) * 32, k0 = (idx / nb) * 32;
    const int tx = threadIdx.x & 31, ty = threadIdx.x >> 5;
#pragma unroll
    for (int i = 0; i < 4; i++)
        tile[ty + i * 8][tx] = W[(size_t)(k0 + ty + i * 8) * N + n0 + tx];
    __syncthreads();
#pragma unroll
    for (int i = 0; i < 4; i++)
        T[(size_t)(n0 + ty + i * 8) * DIM + k0 + tx] = (bf16_t)(tile[tx][ty + i * 8] * scl);
}

// ---------------- GEMM: 128xTN tile, BK=64, T3 2-phase dbuf + XCD panel-locality swizzle ----
// MODE 0: fused QKV (N=2304). Q (pre-scaled via Wq) / K stored plain [b,tok,768];
//         V^T stored KV-PERMUTED so attn's PV A-frags are single contiguous b128.
// MODE 1: proj (fp32 out + bias)
// Round-4 verified: 2-phase dbuf (stage(t+1) before compute(t), ONE barrier/step) -4.4us.
// ROUND-8: 1D grid 768 + bijective XCD swizzle (T1 mechanism): xcd=id&7 owns 4 contiguous
// A-panels (bmi = xcd*4 + slot&3) -> the 24 re-reads of each 196KB A-panel are served from
// that XCD's L2 (786KB resident) instead of L3; the 4 blocks sharing a B-panel are
// dispatch-adjacent (bni = slot>>2) for immediate B reuse. Old 2D grid scattered A-panel
// sharers 32 apart -> cross-XCD, ~300MB of L3 traffic for QKV.
template<int MODE, int TN>
__global__ __launch_bounds__(256)
void gemm_bk64(const bf16_t* __restrict__ Aq, const bf16_t* __restrict__ Akv,
               const bf16_t* __restrict__ Bt,
               bf16_t* __restrict__ Qb, bf16_t* __restrict__ Kb, bf16_t* __restrict__ Vtb,
               float* __restrict__ ofp, const float* __restrict__ bias)
{
    constexpr int K  = DIM;
    constexpr int NT = TN / 32;
    constexpr int ABLK = 128 * 64;
    constexpr int BBLK = TN * 64;
    constexpr int STEP = ABLK + BBLK;                      // one staging buffer
    constexpr int TRELEMS = (MODE == 0) ? 128 * 136 : 0;   // V-transpose epilogue scratch
    constexpr int SELEMS = (2 * STEP > TRELEMS) ? 2 * STEP : TRELEMS;
    __shared__ __align__(16) bf16_t smem[SELEMS];

    const int tid  = threadIdx.x;
    const int wave = tid >> 6, lane = tid & 63;
    const int quad = lane >> 4, l16 = lane & 15, l7 = l16 & 7;

    // XCD panel-locality swizzle: 768 = 8 xcd x (4 bm x 24 bn); bijective.
    const int id  = blockIdx.x;
    const int xcd = id & 7, slot = id >> 3;
    const int bm  = (xcd * 4 + (slot & 3)) * 128;
    const int bn  = (slot >> 2) * TN;
    const int wm = (wave >> 1) * 64, wn = (wave & 1) * (TN / 2);

    const bf16_t* A = (MODE == 0) ? (bn < DIM ? Aq : Akv) : Aq;

    const int srow = tid >> 3;
    const int scol = ((tid & 7) ^ (srow & 7)) * 8;
    const bf16_t* Ag[4];
    const bf16_t* Bg[NT];
#pragma unroll
    for (int i = 0; i < 4; i++)
        Ag[i] = A + (size_t)(bm + i * 32 + srow) * K + scol;
#pragma unroll
    for (int i = 0; i < NT; i++)
        Bg[i] = Bt + (size_t)(bn + i * 32 + srow) * K + scol;

    f32x4 acc[4][NT] = {};

    // prologue: stage K-step 0 into buf 0
    {
        bf16_t* AsL = smem + tid * 8;
        bf16_t* BsL = smem + ABLK + tid * 8;
#pragma unroll
        for (int i = 0; i < 4; i++) async_copy16(Ag[i], AsL + i * 2048);
#pragma unroll
        for (int i = 0; i < NT; i++) async_copy16(Bg[i], BsL + i * 2048);
    }
    __syncthreads();

    for (int t = 0; t < K / 64; t++) {
        bf16_t* Ac = smem + (t & 1) * STEP;
        bf16_t* Bc = Ac + ABLK;

        // prefetch next K-step into the other buffer (latency hides under compute)
        if (t + 1 < K / 64) {
            bf16_t* AsL = smem + ((t + 1) & 1) * STEP + tid * 8;
            bf16_t* BsL = AsL + ABLK;
            const int k1 = (t + 1) * 64;
#pragma unroll
            for (int i = 0; i < 4; i++) async_copy16(Ag[i] + k1, AsL + i * 2048);
#pragma unroll
            for (int i = 0; i < NT; i++) async_copy16(Bg[i] + k1, BsL + i * 2048);
        }

#pragma unroll
        for (int ks = 0; ks < 2; ks++) {
            const int pc = ((ks * 4 + quad) ^ l7) * 8;
            bf16x8 af[4], bfr[NT];
#pragma unroll
            for (int mt = 0; mt < 4; mt++)
                af[mt] = *(const bf16x8*)(&Ac[(wm + mt * 16 + l16) * 64 + pc]);
#pragma unroll
            for (int nt = 0; nt < NT; nt++)
                bfr[nt] = *(const bf16x8*)(&Bc[(wn + nt * 16 + l16) * 64 + pc]);
#pragma unroll
            for (int mt = 0; mt < 4; mt++)
#pragma unroll
                for (int nt = 0; nt < NT; nt++)
                    acc[mt][nt] = __builtin_amdgcn_mfma_f32_16x16x32_bf16(
                        af[mt], bfr[nt], acc[mt][nt], 0, 0, 0);
        }

        // single barrier per K-step: drains the prefetch (issued a compute-phase ago)
        // and fences reads of buf(t) before iteration t+1's prefetch overwrites it
        __syncthreads();
    }

    // ---- epilogue; C layout: col = lane&15, row = quad*4 + reg ----
    if (MODE == 1) {
#pragma unroll
        for (int mt = 0; mt < 4; mt++)
#pragma unroll
            for (int nt = 0; nt < NT; nt++)
#pragma unroll
                for (int r = 0; r < 4; r++) {
                    const int gm = bm + wm + mt * 16 + quad * 4 + r;
                    const int gn = bn + wn + nt * 16 + l16;
                    ofp[(size_t)gm * DIM + gn] = acc[mt][nt][r] + bias[gn];
                }
    } else if (bn < DIM) {
#pragma unroll
        for (int mt = 0; mt < 4; mt++)
#pragma unroll
            for (int nt = 0; nt < NT; nt++)
#pragma unroll
                for (int r = 0; r < 4; r++) {
                    const int gm = bm + wm + mt * 16 + quad * 4 + r;
                    const int gn = bn + wn + nt * 16 + l16;
                    Qb[(size_t)gm * DIM + gn] = (bf16_t)acc[mt][nt][r];
                }
    } else if (bn < 2 * DIM) {
#pragma unroll
        for (int mt = 0; mt < 4; mt++)
#pragma unroll
            for (int nt = 0; nt < NT; nt++)
#pragma unroll
                for (int r = 0; r < 4; r++) {
                    const int gm = bm + wm + mt * 16 + quad * 4 + r;
                    const int gn = bn + wn + nt * 16 + l16 - DIM;
                    Kb[(size_t)gm * DIM + gn] = (bf16_t)acc[mt][nt][r];
                }
    } else {
        // V^T: transpose through LDS, then KV-PERMUTED coalesced 16B stores
        bf16_t* tr = smem;
#pragma unroll
        for (int mt = 0; mt < 4; mt++)
#pragma unroll
            for (int nt = 0; nt < NT; nt++) {
                bf16x4 tv;
#pragma unroll
                for (int r = 0; r < 4; r++) tv[r] = (bf16_t)acc[mt][nt][r];
                *(bf16x4*)(&tr[(wn + nt * 16 + l16) * 136 + wm + mt * 16 + quad * 4]) = tv;
            }
        __syncthreads();
        const int b = bm >> 11, kv0 = bm & 2047;
        const int n2base = bn - 2 * DIM;
        const int cg = tid & 15, cc = cg >> 2, cq = cg & 3;
#pragma unroll
        for (int i = 0; i < TN / 16; i++) {
            const int row = i * 16 + (tid >> 4);
            const int n2 = n2base + row, h = n2 >> 6, d = n2 & 63;
            const bf16x4 lo4 = *(const bf16x4*)(&tr[row * 136 + cc * 32 + cq * 4]);
            const bf16x4 hi4 = *(const bf16x4*)(&tr[row * 136 + cc * 32 + 16 + cq * 4]);
            bf16x8 vv;
#pragma unroll
            for (int j = 0; j < 4; j++) { vv[j] = lo4[j]; vv[4 + j] = hi4[j]; }
            *(bf16x8*)(Vtb + ((size_t)(b * HEADS + h) * HD + d) * NKV + kv0 + cg * 8) = vv;
        }
    }
}

// ---------------- flash attention: 8-wave blocks, KVBLK=64 single-buffer (round-7) ---------
// Pinned at ~39us across 12->24 waves/CU, 4x LDS-traffic variations, dbuf/single-buf:
// multi-resource plateau (MFMA ~10us + L2 KV ~11us + VALU exp/pack, partial overlap).
// Left untouched this round so the GEMM swizzle delta is cleanly attributable.
__global__ __launch_bounds__(512, 6)
void attn_kernel(const bf16_t* __restrict__ Qb, const bf16_t* __restrict__ Kb,
                 const bf16_t* __restrict__ Vt, bf16_t* __restrict__ Xb)
{
    // staging: K[64][64] at [0,4096), V^T[64][64] at [4096,8192) (16KB)
    // epilogue reuse: R f32[64][33] at byte 0; Ob16 [64 q][72 d] bf16 at elem 4224
    __shared__ __align__(16) bf16_t kvbuf[8960];
    __shared__ float libuf[4][16];

    const int tid  = threadIdx.x;
    const int wave = tid >> 6, lane = tid & 63;
    const int quad = lane >> 4, l16 = lane & 15;
    const int l7   = l16 & 7;
    const int kvh = wave & 1, qh = wave >> 1;   // qh 0..3, kvh 0..1

    // XCD-locality swizzle (bijective on 768 = 8 XCDs x 3 heads x 32 q-tiles)
    const int id   = blockIdx.x;
    const int xcd  = id & 7, slot = id >> 3;
    const int bh   = xcd + 8 * (slot >> 5);
    const int b = bh / HEADS, h = bh % HEADS;
    const int q0 = (slot & 31) * 64;

    const bf16_t* Qp = Qb + (size_t)b * NQ * DIM + h * HD;
    const bf16_t* Kp = Kb + (size_t)b * NKV * DIM + h * HD;
    const bf16_t* Vp = Vt + (size_t)(b * HEADS + h) * HD * NKV;

    // staging bases: 512 threads = 64 rows x 8 chunks, one async_copy16 each for K and V.
    // phys LDS chunk sp of row r holds logical chunk sp^(r&7) (bank XOR folded into global
    // addr). Producer V-permutation is LINEAR at 8-chunk granularity (verified r5/r6), so
    // chunk cl of the 64-kv tile sits at global kv0 + cl*8.
    const int sr = tid >> 3, sp = tid & 7;
    const bf16_t* KgA = Kp + (size_t)sr * DIM + ((sp ^ (sr & 7)) * 8);
    const bf16_t* VgA = Vp + (size_t)sr * NKV + ((sp ^ (sr & 7)) * 8);

    // Q B-frags (reg-resident, pre-scaled): q = q0 + qh*16 + l16, k(d) = ks*32 + quad*8 + j
    bf16x8 qf[2];
#pragma unroll
    for (int ks = 0; ks < 2; ks++)
        qf[ks] = *(const bf16x8*)(Qp + (size_t)(q0 + qh * 16 + l16) * DIM
                                  + ks * 32 + quad * 8);

    f32x4 o[4] = {};
    float li = 0.0f;

    for (int t = 0; t < NKV / 64; t++) {
        const int kv0 = t * 64;
        async_copy16(KgA + (size_t)kv0 * DIM, kvbuf + tid * 8);
        async_copy16(VgA + kv0, kvbuf + 4096 + tid * 8);
        __syncthreads();

        // S^T = K @ Q^T : lane holds S^T[kv = kvh*32 + kt*16 + quad*4 + r][q = l16]
        f32x4 s[2] = {};
        __builtin_amdgcn_s_setprio(1);
#pragma unroll
        for (int kt = 0; kt < 2; kt++)
#pragma unroll
            for (int ks = 0; ks < 2; ks++) {
                const bf16x8 kf = *(const bf16x8*)(&kvbuf[
                    (kvh * 32 + kt * 16 + l16) * 64 + (((ks * 4 + quad) ^ l7) * 8)]);
                s[kt] = __builtin_amdgcn_mfma_f32_16x16x32_bf16(kf, qf[ks], s[kt], 0, 0, 0);
            }
        __builtin_amdgcn_s_setprio(0);

        // softmax (no max-subtraction; scale folded in Wq) + pack PV B-frag
        // p[j]: kv = kvh*32 + (j>>2)*16 + quad*4 + (j&3) — matches producer V j-order
        float p[8];
#pragma unroll
        for (int kt = 0; kt < 2; kt++)
#pragma unroll
            for (int r = 0; r < 4; r++) p[kt * 4 + r] = fast_exp2(s[kt][r]);
        float rs = 0.0f;
#pragma unroll
        for (int j = 0; j < 8; j++) rs += p[j];
        li += rs;
        bf16x8 pb;
#pragma unroll
        for (int j = 0; j < 8; j++) pb[j] = (bf16_t)p[j];

        // O^T += V^T @ P^T over this wave's 32-kv half (single k-step)
        __builtin_amdgcn_s_setprio(1);
#pragma unroll
        for (int dt = 0; dt < 4; dt++) {
            const bf16x8 vf = *(const bf16x8*)(&kvbuf[
                4096 + (dt * 16 + l16) * 64 + (((kvh * 4 + quad) ^ l7) * 8)]);
            o[dt] = __builtin_amdgcn_mfma_f32_16x16x32_bf16(vf, pb, o[dt], 0, 0, 0);
        }
        __builtin_amdgcn_s_setprio(0);
        __syncthreads();
    }

    // li: reduce across quads (quads covered disjoint kv rows of the half)
    li += __shfl_xor(li, 16);
    li += __shfl_xor(li, 32);
    if (kvh == 1 && quad == 0) libuf[qh][l16] = li;

    // 2-phase kv-half merge: R f32[64 d][33] (8.4KB), Ob16 [64 q][72 d] at elem 4224
    float*  R    = (float*)&kvbuf[0];
    bf16_t* Ob16 = kvbuf + 4224;
#pragma unroll
    for (int ph = 0; ph < 2; ph++) {
        if (kvh == 1 && (qh >> 1) == ph) {
#pragma unroll
            for (int dt = 0; dt < 4; dt++)
#pragma unroll
                for (int r = 0; r < 4; r++)
                    R[(dt * 16 + quad * 4 + r) * 33 + (qh & 1) * 16 + l16] = o[dt][r];
        }
        __syncthreads();
        if (kvh == 0 && (qh >> 1) == ph) {
            const float inv = 1.0f / (li + libuf[qh][l16]);
#pragma unroll
            for (int dt = 0; dt < 4; dt++) {
                bf16x4 ov;
#pragma unroll
                for (int r = 0; r < 4; r++)
                    ov[r] = (bf16_t)((o[dt][r]
                                      + R[(dt * 16 + quad * 4 + r) * 33 + (qh & 1) * 16 + l16])
                                     * inv);
                *(bf16x4*)(&Ob16[(qh * 16 + l16) * 72 + dt * 16 + quad * 4]) = ov;
            }
        }
        __syncthreads();
    }
    {
        const int row = tid >> 3, ch = (tid & 7) * 8;
        bf16_t* dst = Xb + (size_t)(b * NQ + q0 + row) * DIM + h * HD + ch;
        *(bf16x8*)(dst) = *(const bf16x8*)(&Ob16[row * 72 + ch]);
    }
}

extern "C" void kernel_launch(void* const* d_in, const int* in_sizes, int n_in,
                              void* d_out, int out_size, void* d_ws, size_t ws_size,
                              hipStream_t stream)
{
    const float* qs    = (const float*)d_in[0];
    const float* kvs   = (const float*)d_in[1];
    const float* Wq    = (const float*)d_in[2];
    const float* Wkv   = (const float*)d_in[3];
    const float* Wproj = (const float*)d_in[4];
    const float* bproj = (const float*)d_in[5];
    float* out = (float*)d_out;

    bf16_t* w = (bf16_t*)d_ws;
    bf16_t* qs_bf  = w;  w += (size_t)MROWS * DIM;
    bf16_t* kvs_bf = w;  w += (size_t)MROWS * DIM;
    bf16_t* Wt     = w;  w += (size_t)NQKV * DIM;   // Wqt | Wkvt contiguous
    bf16_t* Wprojt = w;  w += (size_t)DIM * DIM;
    bf16_t* Qb     = w;  w += (size_t)MROWS * DIM;
    bf16_t* Kb     = w;  w += (size_t)MROWS * DIM;
    bf16_t* Vtb    = w;  w += (size_t)MROWS * DIM;
    bf16_t* Xb     = qs_bf;   // qs_bf dead after QKV GEMM

    const float escale = 0.125f * 1.44269504088896341f;  // Dh^-0.5 * log2(e), folded into Wq
    prep_kernel<<<dim3(MROWS * DIM / 2048, 1, 5), 256, 0, stream>>>(
        qs, qs_bf, kvs, kvs_bf, Wq, Wkv, Wproj, Wt, escale);

    // 1D 768-block grids with XCD panel-locality swizzle (see kernel comment)
    gemm_bk64<0, 96><<<dim3(768), 256, 0, stream>>>(
        qs_bf, kvs_bf, Wt, Qb, Kb, Vtb, nullptr, nullptr);
    // 768 blocks x 512 threads = 3 blocks/CU x 8 waves = 24 waves/CU
    attn_kernel<<<dim3(768), 512, 0, stream>>>(Qb, Kb, Vtb, Xb);
    gemm_bk64<1, 32><<<dim3(768), 256, 0, stream>>>(
        Xb, nullptr, Wprojt, nullptr, nullptr, nullptr, out, bproj);
}